// Round 2
// 709.452 us; speedup vs baseline: 1.0545x; 1.0545x over previous
//
#include <hip/hip_runtime.h>
#include <stdint.h>

#define TOKENS 65536
#define KDIM 1024
#define NDIM 1024
#define MROWS 65664            // TOKENS + 128, multiple of 128
#define ROWTILES 513           // MROWS / 128
#define BK 64

using short8 = __attribute__((ext_vector_type(8))) short;
using f32x4  = __attribute__((ext_vector_type(4))) float;

// async global->LDS, 16B per lane; LDS dest must be wave-uniform base (+lane*16 in HW)
#define ASYNC_COPY16(g, l) __builtin_amdgcn_global_load_lds( \
    (const __attribute__((address_space(1))) void*)(g),      \
    (__attribute__((address_space(3))) void*)(l), 16, 0, 0)

__device__ __forceinline__ short f2bf(float f) {
    union { float f; unsigned u; } c; c.f = f;
    unsigned r = c.u + 0x7FFFu + ((c.u >> 16) & 1u);   // round-to-nearest-even
    return (short)(r >> 16);
}

// ---------- mask format detection (runtime, value-based — verified in round 0) ----------
// 0=int32{0,1}, 1=packed bytes, 2=float32. Parallel: 64 blocks x 256 thr, 1 word each.
__global__ __launch_bounds__(256) void detect_mask_fmt(const unsigned* __restrict__ mask,
                                                       int* __restrict__ hdr) {
    int i = blockIdx.x * 256 + threadIdx.x;           // 16384 words = 64KB window
    unsigned w = mask[i];
    int mode = 0;
    if (w == 0x3F800000u)      mode = 2;              // float 1.0 pattern
    else if (w > 1u)           mode = 1;              // packed bool bytes
    if (mode) atomicMax(&hdr[2], mode);
}

__device__ __forceinline__ bool read_mask(const void* mask, int fmt, int t) {
    if (fmt == 2) return ((const float*)mask)[t] != 0.0f;
    if (fmt == 1) return ((const unsigned char*)mask)[t] != 0;
    return ((const int*)mask)[t] != 0;
}

// ---------- slot assignment: visual ascending from 0, text descending from MROWS-1 ----------
__global__ __launch_bounds__(256) void route_assign(const void* __restrict__ mask,
                                                    int* __restrict__ rowmap,
                                                    int* __restrict__ slotmap,
                                                    int* __restrict__ hdr) {
    const int tid  = threadIdx.x;
    const int lane = tid & 63;
    const int wid  = tid >> 6;
    const int t    = blockIdx.x * 256 + tid;
    const int fmt  = hdr[2];
    const bool m   = read_mask(mask, fmt, t);

    unsigned long long bal = __ballot(m);
    int vpre = __popcll(bal & ((1ull << lane) - 1ull));
    int vcnt = __popcll(bal);
    int tpre = lane - vpre;
    int tcnt = 64 - vcnt;

    __shared__ int cv[4], ct[4], ov[4], ot[4];
    __shared__ int bv, bt;
    if (lane == 0) { cv[wid] = vcnt; ct[wid] = tcnt; }
    __syncthreads();
    if (tid == 0) {
        int sv = 0, st = 0;
        for (int w = 0; w < 4; ++w) { ov[w] = sv; sv += cv[w]; ot[w] = st; st += ct[w]; }
        bv = atomicAdd(&hdr[0], sv);   // hdr[0] ends as Mv
        bt = atomicAdd(&hdr[1], st);
    }
    __syncthreads();
    int slot = m ? (bv + ov[wid] + vpre)
                 : (MROWS - 1 - (bt + ot[wid] + tpre));
    rowmap[slot] = t;
    slotmap[t] = slot;
}

// ---------- gather fp32 row -> bf16 compact row (1 wave per token) ----------
__global__ __launch_bounds__(256) void gather_convert(const float* __restrict__ x,
                                                      const int* __restrict__ slotmap,
                                                      short* __restrict__ Abuf) {
    const int lane = threadIdx.x & 63;
    const int t    = blockIdx.x * 4 + (threadIdx.x >> 6);
    const int slot = slotmap[t];
    const float* src = x + (size_t)t * KDIM;
    short* dst = Abuf + (size_t)slot * KDIM;
#pragma unroll
    for (int p = 0; p < 4; ++p) {
        int k = p * 256 + lane * 4;
        float4 v = *(const float4*)(src + k);
        short4 o;
        o.x = f2bf(v.x); o.y = f2bf(v.y); o.z = f2bf(v.z); o.w = f2bf(v.w);
        *(short4*)(dst + k) = o;
    }
}

// ---------- weights fp32 -> bf16 ----------
__global__ __launch_bounds__(256) void convert_weights(const float* __restrict__ wv,
                                                       const float* __restrict__ wt,
                                                       short* __restrict__ ovp,
                                                       short* __restrict__ otp) {
    int i = (blockIdx.x * 256 + threadIdx.x) * 4;
    const float* src; short* dst; int off;
    if (i < NDIM * KDIM) { src = wv; dst = ovp; off = i; }
    else                 { src = wt; dst = otp; off = i - NDIM * KDIM; }
    float4 v = *(const float4*)(src + off);
    short4 o;
    o.x = f2bf(v.x); o.y = f2bf(v.y); o.z = f2bf(v.z); o.w = f2bf(v.w);
    *(short4*)(dst + off) = o;
}

// ---------- routed GEMM: out[token, n] = sum_k A[row,k] * Wsel[n,k] ----------
// m97 structure: 128x128 tile, BK=64, 4 waves, each wave 4x4 frags of mfma_f32_16x16x32_bf16,
// 32 MFMA per K-step between one barrier pair. Flattened grid with XCD-aware swizzle.
__global__ __launch_bounds__(256) void gemm_routed(const short* __restrict__ Abuf,
                                                   const short* __restrict__ Wv,
                                                   const short* __restrict__ Wt,
                                                   const int* __restrict__ rowmap,
                                                   const int* __restrict__ hdr,
                                                   float* __restrict__ out) {
    __shared__ __align__(16) short As[128 * BK];   // 16 KB, row-major [128][64]
    __shared__ __align__(16) short Bs[128 * BK];   // 16 KB
    __shared__ int rmap_s[128];

    // 4104 blocks = 8 * 513 (evenly divisible -> bijective transpose swizzle).
    // XCD x (= bid%8) gets work ids [513x, 513x+513): ~64 contiguous row-tiles
    // with all 8 n-tiles -> A-tile refetch becomes L2-local per XCD.
    const int bid = blockIdx.x;
    const int w   = (bid & 7) * ROWTILES + (bid >> 3);
    const int r0  = (w >> 3) * 128;
    const int n0  = (w & 7) * 128;

    const int Mv = hdr[0];
    if (r0 == Mv) return;                          // gap-only tile (uniform exit)
    const short* Wsel = (r0 < Mv) ? Wv : Wt;       // straddle tiles: real rows one-sided, pad rows skipped

    const int tid  = threadIdx.x;
    const int lane = tid & 63;
    const int wvid = tid >> 6;

    if (tid < 128) rmap_s[tid] = rowmap[r0 + tid];

    // staging coords: per wave, 4 chunks of (8 rows x 64 cols) for A and for B.
    // chunk c: lane covers row = wvid*32 + c*8 + (lane>>3), col = (lane&7)*8 shorts (16B)
    const int srow = wvid * 32 + (lane >> 3);
    const int scol = (lane & 7) * 8;
    const short* aP = Abuf + (size_t)(r0 + srow) * KDIM + scol;
    const short* bP = Wsel + (size_t)(n0 + srow) * KDIM + scol;
    char* lA = (char*)As + wvid * 4096;            // wave-uniform LDS bases (32 rows * 128B)
    char* lB = (char*)Bs + wvid * 4096;

    f32x4 acc[4][4];
#pragma unroll
    for (int i = 0; i < 4; ++i)
#pragma unroll
        for (int j = 0; j < 4; ++j) acc[i][j] = f32x4{0.f, 0.f, 0.f, 0.f};

    const int wm = (wvid & 1) * 64;
    const int wn = (wvid >> 1) * 64;
    const short* aF = As + (wm + (lane & 15)) * BK + (lane >> 4) * 8;
    const short* bF = Bs + (wn + (lane & 15)) * BK + (lane >> 4) * 8;

    for (int kt = 0; kt < KDIM / BK; ++kt) {
        const int k0 = kt * BK;
        __syncthreads();                           // prior compute done before overwrite
#pragma unroll
        for (int c = 0; c < 4; ++c) {
            ASYNC_COPY16(aP + (size_t)c * 8 * KDIM + k0, lA + c * 1024);
            ASYNC_COPY16(bP + (size_t)c * 8 * KDIM + k0, lB + c * 1024);
        }
        __syncthreads();                           // vmcnt(0) drain -> staged data visible

#pragma unroll
        for (int ks = 0; ks < 2; ++ks) {
            short8 af[4], bfr[4];
#pragma unroll
            for (int mt = 0; mt < 4; ++mt) af[mt]  = *(const short8*)(aF + mt * 16 * BK + ks * 32);
#pragma unroll
            for (int nt = 0; nt < 4; ++nt) bfr[nt] = *(const short8*)(bF + nt * 16 * BK + ks * 32);
#pragma unroll
            for (int mt = 0; mt < 4; ++mt)
#pragma unroll
                for (int nt = 0; nt < 4; ++nt)
                    acc[mt][nt] = __builtin_amdgcn_mfma_f32_16x16x32_bf16(
                        af[mt], bfr[nt], acc[mt][nt], 0, 0, 0);
        }
    }

    // epilogue: C/D layout col=lane&15, row=(lane>>4)*4+reg; scatter by rowmap
    const int col = n0 + wn + (lane & 15);
#pragma unroll
    for (int mt = 0; mt < 4; ++mt) {
        int rb = wm + mt * 16 + ((lane >> 4) << 2);
#pragma unroll
        for (int i = 0; i < 4; ++i) {
            int token = rmap_s[rb + i];
            if (token < 0) continue;               // padding row
            float* orow = out + (size_t)token * NDIM + col;
            orow[0]  = acc[mt][0][i];
            orow[16] = acc[mt][1][i];
            orow[32] = acc[mt][2][i];
            orow[48] = acc[mt][3][i];
        }
    }
}

// ---------- fp32 fallback (only if workspace too small) ----------
__global__ __launch_bounds__(256) void fallback_matvec(const float* __restrict__ x,
                                                       const void* __restrict__ mask,
                                                       const float* __restrict__ wv,
                                                       const float* __restrict__ wt,
                                                       const int* __restrict__ hdr,
                                                       float* __restrict__ out) {
    __shared__ float xs[KDIM];
    const int t = blockIdx.x;
    const int fmt = hdr[2];
    const bool m = read_mask(mask, fmt, t);
    const float* w = m ? wv : wt;
    const float* src = x + (size_t)t * KDIM;
    for (int k = threadIdx.x; k < KDIM; k += 256) xs[k] = src[k];
    __syncthreads();
    for (int n = threadIdx.x; n < NDIM; n += 256) {
        const float* wr = w + (size_t)n * KDIM;
        float s = 0.f;
        for (int k = 0; k < KDIM; ++k) s += xs[k] * wr[k];
        out[(size_t)t * NDIM + n] = s;
    }
}

extern "C" void kernel_launch(void* const* d_in, const int* in_sizes, int n_in,
                              void* d_out, int out_size, void* d_ws, size_t ws_size,
                              hipStream_t stream) {
    const float* x    = (const float*)d_in[0];
    const void*  mask = d_in[1];
    const float* w_v  = (const float*)d_in[2];
    const float* w_t  = (const float*)d_in[3];
    float* out = (float*)d_out;

    char* ws = (char*)d_ws;
    // workspace layout (all 16B-aligned offsets)
    int*   hdr     = (int*)ws;                      // [0]=cnt_v [1]=cnt_t [2]=mask fmt
    int*   rowmap  = (int*)(ws + 4096);             // MROWS ints
    int*   slotmap = (int*)(ws + 270336);           // TOKENS ints
    short* wvb     = (short*)(ws + 532480);         // 2 MB
    short* wtb     = (short*)(ws + 2629632);        // 2 MB
    short* Abuf    = (short*)(ws + 4726784);        // MROWS*1024 bf16 = 134.5 MB
    const size_t need = 4726784ull + (size_t)MROWS * KDIM * sizeof(short);

    if (ws_size >= need) {
        hipMemsetAsync(hdr, 0, 16, stream);
        hipMemsetAsync(rowmap, 0xFF, MROWS * sizeof(int), stream);   // -1 sentinels
        detect_mask_fmt<<<64, 256, 0, stream>>>((const unsigned*)mask, hdr);
        route_assign<<<TOKENS / 256, 256, 0, stream>>>(mask, rowmap, slotmap, hdr);
        gather_convert<<<TOKENS / 4, 256, 0, stream>>>(x, slotmap, Abuf);
        convert_weights<<<(2 * NDIM * KDIM) / (256 * 4), 256, 0, stream>>>(w_v, w_t, wvb, wtb);
        gemm_routed<<<8 * ROWTILES, 256, 0, stream>>>(Abuf, wvb, wtb, rowmap, hdr, out);
    } else {
        hipMemsetAsync(hdr, 0, 16, stream);
        detect_mask_fmt<<<64, 256, 0, stream>>>((const unsigned*)mask, hdr);
        fallback_matvec<<<TOKENS, 256, 0, stream>>>(x, mask, w_v, w_t, hdr, out);
    }
}

// Round 3
// 653.931 us; speedup vs baseline: 1.1441x; 1.0849x over previous
//
#include <hip/hip_runtime.h>
#include <stdint.h>

#define TOKENS 65536
#define KDIM 1024
#define NDIM 1024
#define MROWS 65792            // TOKENS + 256, multiple of 256 (gap=256 -> no straddle at BM=256)
#define ROWTILES 257           // MROWS / 256
#define NTILES 4               // NDIM / 256
#define NWG (ROWTILES * NTILES)
#define BK 64
#define NT 16                  // KDIM / BK

using short8 = __attribute__((ext_vector_type(8))) short;
using f32x4  = __attribute__((ext_vector_type(4))) float;

// async global->LDS, 16B per lane; LDS dest must be wave-uniform base (+lane*16 in HW)
#define ASYNC_COPY16(g, l) __builtin_amdgcn_global_load_lds( \
    (const __attribute__((address_space(1))) void*)(g),      \
    (__attribute__((address_space(3))) void*)(l), 16, 0, 0)

__device__ __forceinline__ short f2bf(float f) {
    union { float f; unsigned u; } c; c.f = f;
    unsigned r = c.u + 0x7FFFu + ((c.u >> 16) & 1u);   // round-to-nearest-even
    return (short)(r >> 16);
}

// ---------- mask format detection (runtime, value-based — verified) ----------
__global__ __launch_bounds__(256) void detect_mask_fmt(const unsigned* __restrict__ mask,
                                                       int* __restrict__ hdr) {
    int i = blockIdx.x * 256 + threadIdx.x;
    unsigned w = mask[i];
    int mode = 0;
    if (w == 0x3F800000u)      mode = 2;              // float 1.0
    else if (w > 1u)           mode = 1;              // packed bool bytes
    if (mode) atomicMax(&hdr[2], mode);
}

__device__ __forceinline__ bool read_mask(const void* mask, int fmt, int t) {
    if (fmt == 2) return ((const float*)mask)[t] != 0.0f;
    if (fmt == 1) return ((const unsigned char*)mask)[t] != 0;
    return ((const int*)mask)[t] != 0;
}

// ---------- slot assignment: visual ascending from 0, text descending from MROWS-1 ----------
__global__ __launch_bounds__(256) void route_assign(const void* __restrict__ mask,
                                                    int* __restrict__ rowmap,
                                                    int* __restrict__ slotmap,
                                                    int* __restrict__ hdr) {
    const int tid  = threadIdx.x;
    const int lane = tid & 63;
    const int wid  = tid >> 6;
    const int t    = blockIdx.x * 256 + tid;
    const int fmt  = hdr[2];
    const bool m   = read_mask(mask, fmt, t);

    unsigned long long bal = __ballot(m);
    int vpre = __popcll(bal & ((1ull << lane) - 1ull));
    int vcnt = __popcll(bal);
    int tpre = lane - vpre;
    int tcnt = 64 - vcnt;

    __shared__ int cv[4], ct[4], ov[4], ot[4];
    __shared__ int bv, bt;
    if (lane == 0) { cv[wid] = vcnt; ct[wid] = tcnt; }
    __syncthreads();
    if (tid == 0) {
        int sv = 0, st = 0;
        for (int w = 0; w < 4; ++w) { ov[w] = sv; sv += cv[w]; ot[w] = st; st += ct[w]; }
        bv = atomicAdd(&hdr[0], sv);   // hdr[0] ends as Mv
        bt = atomicAdd(&hdr[1], st);
    }
    __syncthreads();
    int slot = m ? (bv + ov[wid] + vpre)
                 : (MROWS - 1 - (bt + ot[wid] + tpre));
    rowmap[slot] = t;
    slotmap[t] = slot;
}

// ---------- gather fp32 row -> bf16 compact row (1 wave per token) ----------
__global__ __launch_bounds__(256) void gather_convert(const float* __restrict__ x,
                                                      const int* __restrict__ slotmap,
                                                      short* __restrict__ Abuf) {
    const int lane = threadIdx.x & 63;
    const int t    = blockIdx.x * 4 + (threadIdx.x >> 6);
    const int slot = slotmap[t];
    const float* src = x + (size_t)t * KDIM;
    short* dst = Abuf + (size_t)slot * KDIM;
#pragma unroll
    for (int p = 0; p < 4; ++p) {
        int k = p * 256 + lane * 4;
        float4 v = *(const float4*)(src + k);
        short4 o;
        o.x = f2bf(v.x); o.y = f2bf(v.y); o.z = f2bf(v.z); o.w = f2bf(v.w);
        *(short4*)(dst + k) = o;
    }
}

// ---------- weights fp32 -> bf16 ----------
__global__ __launch_bounds__(256) void convert_weights(const float* __restrict__ wv,
                                                       const float* __restrict__ wt,
                                                       short* __restrict__ ovp,
                                                       short* __restrict__ otp) {
    int i = (blockIdx.x * 256 + threadIdx.x) * 4;
    const float* src; short* dst; int off;
    if (i < NDIM * KDIM) { src = wv; dst = ovp; off = i; }
    else                 { src = wt; dst = otp; off = i - NDIM * KDIM; }
    float4 v = *(const float4*)(src + off);
    short4 o;
    o.x = f2bf(v.x); o.y = f2bf(v.y); o.z = f2bf(v.z); o.w = f2bf(v.w);
    *(short4*)(dst + off) = o;
}

// ============ 256x256 8-phase GEMM (T2 swizzle + T3/T4 counted vmcnt + T5 setprio) ============
// 8 waves (2Mx4N), per-wave 128x64 output, BK=64, dbuf LDS 128KB.
// LDS halves: A[buf][h] = rows h*128..h*128+127 (16KB each); same for B.
// XOR bank swizzle: byte-in-row ^= (row&7)<<4 on ds_read; staged via pre-swizzled global src (rule #21).
// Region safety: B-region fully ds_read in ph1 -> restaged ph2/ph3; A-region done ph3 -> restaged ph4;
// every stage issue is >=1 s_barrier after the last ds_read of its region.
// vmcnt(8) at each K-tile boundary: outstanding <= {next K-tile's 8 loads}; current K-tile guaranteed landed.

#define QUAD(MB, NB)                                                              \
    do {                                                                          \
        _Pragma("unroll") for (int m_ = 0; m_ < 4; ++m_)                          \
        _Pragma("unroll") for (int n_ = 0; n_ < 2; ++n_)                          \
        _Pragma("unroll") for (int ks_ = 0; ks_ < 2; ++ks_)                       \
            acc[(MB) + m_][(NB) + n_] = __builtin_amdgcn_mfma_f32_16x16x32_bf16(  \
                a[2 * m_ + ks_], b[2 * ((NB) + n_) + ks_],                        \
                acc[(MB) + m_][(NB) + n_], 0, 0, 0);                              \
    } while (0)

template<bool STAGE, int ENDM>   // ENDM: 0 = vmcnt(8)+bar, 1 = vmcnt(0)+bar, 2 = none
__device__ __forceinline__ void kstep(const char* pA, const char* pB,
                                      char* lA, char* lB,
                                      const short* aS, const short* bS,
                                      f32x4 (&acc)[8][4], int xorhi) {
    short8 a[8], b[8];
    // ---- ph1: ds_read A[m0..3] (8) + B[all] (8)
#pragma unroll
    for (int m = 0; m < 4; ++m) {
        a[2*m]   = *(const short8*)(pA + m * 2048 + (0  ^ xorhi));
        a[2*m+1] = *(const short8*)(pA + m * 2048 + (64 ^ xorhi));
    }
#pragma unroll
    for (int n = 0; n < 4; ++n) {
        b[2*n]   = *(const short8*)(pB + n * 2048 + (0  ^ xorhi));
        b[2*n+1] = *(const short8*)(pB + n * 2048 + (64 ^ xorhi));
    }
    __builtin_amdgcn_s_barrier();
    asm volatile("s_waitcnt lgkmcnt(0)" ::: "memory");
    __builtin_amdgcn_sched_barrier(0);
    __builtin_amdgcn_s_setprio(1);
    QUAD(0, 0);
    __builtin_amdgcn_s_setprio(0);
    __builtin_amdgcn_s_barrier();
    // ---- ph2: stage B half0 of kt+2 (B-region of this buf fully read in ph1)
    if (STAGE) {
        ASYNC_COPY16(bS,                     lB);
        ASYNC_COPY16(bS + (size_t)64 * KDIM, lB + 8192);
    }
    __builtin_amdgcn_s_barrier();
    __builtin_amdgcn_s_setprio(1);
    QUAD(0, 2);
    __builtin_amdgcn_s_setprio(0);
    __builtin_amdgcn_s_barrier();
    // ---- ph3: ds_read A[m4..7]; stage B half1
#pragma unroll
    for (int m = 0; m < 4; ++m) {
        a[2*m]   = *(const short8*)(pA + (4 + m) * 2048 + (0  ^ xorhi));
        a[2*m+1] = *(const short8*)(pA + (4 + m) * 2048 + (64 ^ xorhi));
    }
    if (STAGE) {
        ASYNC_COPY16(bS + (size_t)128 * KDIM, lB + 16384);
        ASYNC_COPY16(bS + (size_t)192 * KDIM, lB + 16384 + 8192);
    }
    __builtin_amdgcn_s_barrier();
    asm volatile("s_waitcnt lgkmcnt(0)" ::: "memory");
    __builtin_amdgcn_sched_barrier(0);
    __builtin_amdgcn_s_setprio(1);
    QUAD(4, 0);
    __builtin_amdgcn_s_setprio(0);
    __builtin_amdgcn_s_barrier();
    // ---- ph4: stage A half0+half1 (A-region fully read in ph3)
    if (STAGE) {
        ASYNC_COPY16(aS,                      lA);
        ASYNC_COPY16(aS + (size_t)64  * KDIM, lA + 8192);
        ASYNC_COPY16(aS + (size_t)128 * KDIM, lA + 16384);
        ASYNC_COPY16(aS + (size_t)192 * KDIM, lA + 16384 + 8192);
    }
    __builtin_amdgcn_s_barrier();
    __builtin_amdgcn_s_setprio(1);
    QUAD(4, 2);
    __builtin_amdgcn_s_setprio(0);
    if (ENDM == 0) asm volatile("s_waitcnt vmcnt(8)" ::: "memory");
    if (ENDM == 1) asm volatile("s_waitcnt vmcnt(0)" ::: "memory");
    if (ENDM < 2)  __builtin_amdgcn_s_barrier();
}

__device__ __forceinline__ void stage_ktile(char* lA, char* lB,
                                            const short* aS, const short* bS) {
    ASYNC_COPY16(aS,                      lA);
    ASYNC_COPY16(aS + (size_t)64  * KDIM, lA + 8192);
    ASYNC_COPY16(aS + (size_t)128 * KDIM, lA + 16384);
    ASYNC_COPY16(aS + (size_t)192 * KDIM, lA + 16384 + 8192);
    ASYNC_COPY16(bS,                      lB);
    ASYNC_COPY16(bS + (size_t)64  * KDIM, lB + 8192);
    ASYNC_COPY16(bS + (size_t)128 * KDIM, lB + 16384);
    ASYNC_COPY16(bS + (size_t)192 * KDIM, lB + 16384 + 8192);
}

__global__ __launch_bounds__(512, 2) void gemm_routed(const short* __restrict__ Abuf,
                                                      const short* __restrict__ Wv,
                                                      const short* __restrict__ Wt,
                                                      const int* __restrict__ rowmap,
                                                      const int* __restrict__ hdr,
                                                      float* __restrict__ out) {
    __shared__ __align__(16) short As[2 * 256 * 64];   // 64 KB
    __shared__ __align__(16) short Bs[2 * 256 * 64];   // 64 KB
    __shared__ int rmap_s[256];

    // bijective XCD swizzle (m204 variant; NWG=1028, q=128, r=4)
    const int q = NWG / 8, r = NWG % 8;
    const int xcd = blockIdx.x & 7, ii = blockIdx.x >> 3;
    const int wgid = (xcd < r ? xcd * (q + 1) : r * (q + 1) + (xcd - r) * q) + ii;
    const int r0 = (wgid >> 2) * 256;
    const int n0 = (wgid & 3) * 256;

    const int Mv = hdr[0];
    if (r0 == Mv) return;                          // gap-only tile (uniform exit, before any barrier)
    const short* Wsel = (r0 < Mv) ? Wv : Wt;       // gap=256 -> tiles never hold both real kinds

    const int tid  = threadIdx.x;
    const int lane = tid & 63;
    const int wvid = tid >> 6;
    const int wr   = wvid >> 2;                    // 0..1: A half / 128-row half
    const int wc   = wvid & 3;                     // 0..3: 64-col quarter

    if (tid < 256) rmap_s[tid] = rowmap[r0 + tid];

    // staging: thread covers rows (arow + l*64 + h*128), pre-swizzled 16B chunk achk
    const int arow = tid >> 3;                     // 0..63
    const int achk = (tid & 7) ^ (arow & 7);       // inverse of read-side XOR
    const short* aSrc = Abuf + (size_t)(r0 + arow) * KDIM + achk * 8;
    const short* bSrc = Wsel + (size_t)(n0 + arow) * KDIM + achk * 8;
    char* lA0 = (char*)As + wvid * 1024;           // wave-uniform dest bases (lane*16 by HW)
    char* lB0 = (char*)Bs + wvid * 1024;
    char* lA1 = lA0 + 32768;
    char* lB1 = lB0 + 32768;

    // fragment-read bases: row_local*128 + ((ks*64 + (lane>>4)*16) ^ ((row_local&7)<<4))
    const int xorhi = (lane & 4) << 4;
    const char* aRd = (const char*)As + wr * 16384 + (lane & 15) * 128
                      + (((lane >> 4) * 16) ^ ((lane & 3) << 4));
    const char* bRd = (const char*)Bs + (wc >> 1) * 16384
                      + (((wc & 1) * 64 + (lane & 15)) * 128)
                      + (((lane >> 4) * 16) ^ ((lane & 3) << 4));
    const char* pA0 = aRd;       const char* pA1 = aRd + 32768;
    const char* pB0 = bRd;       const char* pB1 = bRd + 32768;

    f32x4 acc[8][4];
#pragma unroll
    for (int m = 0; m < 8; ++m)
#pragma unroll
        for (int n = 0; n < 4; ++n) acc[m][n] = f32x4{0.f, 0.f, 0.f, 0.f};

    // prologue: stage kt0 (buf0) + kt1 (buf1); wait kt0 (8 newest = kt1 may fly)
    stage_ktile(lA0, lB0, aSrc + 0 * BK, bSrc + 0 * BK);
    stage_ktile(lA1, lB1, aSrc + 1 * BK, bSrc + 1 * BK);
    asm volatile("s_waitcnt vmcnt(8)" ::: "memory");
    __builtin_amdgcn_s_barrier();

    // main loop: kt pairs; each kstep stages kt+2 into its own (just-freed) buffer
    for (int it = 0; it < 7; ++it) {
        const int k2 = 2 * it + 2, k3 = 2 * it + 3;
        kstep<true, 0>(pA0, pB0, lA0, lB0, aSrc + k2 * BK, bSrc + k2 * BK, acc, xorhi);
        kstep<true, 0>(pA1, pB1, lA1, lB1, aSrc + k3 * BK, bSrc + k3 * BK, acc, xorhi);
    }
    kstep<false, 1>(pA0, pB0, lA0, lB0, aSrc, bSrc, acc, xorhi);   // kt14: drain all (kt15 loads)
    kstep<false, 2>(pA1, pB1, lA1, lB1, aSrc, bSrc, acc, xorhi);   // kt15

    // epilogue: C/D layout col=lane&15, row=(lane>>4)*4+reg; scatter by rowmap
    const int colbase = n0 + wc * 64 + (lane & 15);
#pragma unroll
    for (int m = 0; m < 8; ++m) {
        const int rb = wr * 128 + m * 16 + ((lane >> 4) << 2);
#pragma unroll
        for (int i2 = 0; i2 < 4; ++i2) {
            int token = rmap_s[rb + i2];
            if (token < 0) continue;               // padding row
            float* orow = out + (size_t)token * NDIM + colbase;
            orow[0]  = acc[m][0][i2];
            orow[16] = acc[m][1][i2];
            orow[32] = acc[m][2][i2];
            orow[48] = acc[m][3][i2];
        }
    }
}

// ---------- fp32 fallback (only if workspace too small) ----------
__global__ __launch_bounds__(256) void fallback_matvec(const float* __restrict__ x,
                                                       const void* __restrict__ mask,
                                                       const float* __restrict__ wv,
                                                       const float* __restrict__ wt,
                                                       const int* __restrict__ hdr,
                                                       float* __restrict__ out) {
    __shared__ float xs[KDIM];
    const int t = blockIdx.x;
    const int fmt = hdr[2];
    const bool m = read_mask(mask, fmt, t);
    const float* w = m ? wv : wt;
    const float* src = x + (size_t)t * KDIM;
    for (int k = threadIdx.x; k < KDIM; k += 256) xs[k] = src[k];
    __syncthreads();
    for (int n = threadIdx.x; n < NDIM; n += 256) {
        const float* wr = w + (size_t)n * KDIM;
        float s = 0.f;
        for (int k = 0; k < KDIM; ++k) s += xs[k] * wr[k];
        out[(size_t)t * NDIM + n] = s;
    }
}

extern "C" void kernel_launch(void* const* d_in, const int* in_sizes, int n_in,
                              void* d_out, int out_size, void* d_ws, size_t ws_size,
                              hipStream_t stream) {
    const float* x    = (const float*)d_in[0];
    const void*  mask = d_in[1];
    const float* w_v  = (const float*)d_in[2];
    const float* w_t  = (const float*)d_in[3];
    float* out = (float*)d_out;

    char* ws = (char*)d_ws;
    // workspace layout (all 16B-aligned offsets)
    int*   hdr     = (int*)ws;                      // [0]=cnt_v [1]=cnt_t [2]=mask fmt
    int*   rowmap  = (int*)(ws + 4096);             // MROWS ints (263168 B < 266240 gap)
    int*   slotmap = (int*)(ws + 270336);           // TOKENS ints
    short* wvb     = (short*)(ws + 532480);         // 2 MB
    short* wtb     = (short*)(ws + 2629632);        // 2 MB
    short* Abuf    = (short*)(ws + 4726784);        // MROWS*1024 bf16
    const size_t need = 4726784ull + (size_t)MROWS * KDIM * sizeof(short);

    if (ws_size >= need) {
        hipMemsetAsync(hdr, 0, 16, stream);
        hipMemsetAsync(rowmap, 0xFF, MROWS * sizeof(int), stream);   // -1 sentinels
        detect_mask_fmt<<<64, 256, 0, stream>>>((const unsigned*)mask, hdr);
        route_assign<<<TOKENS / 256, 256, 0, stream>>>(mask, rowmap, slotmap, hdr);
        gather_convert<<<TOKENS / 4, 256, 0, stream>>>(x, slotmap, Abuf);
        convert_weights<<<(2 * NDIM * KDIM) / (256 * 4), 256, 0, stream>>>(w_v, w_t, wvb, wtb);
        gemm_routed<<<NWG, 512, 0, stream>>>(Abuf, wvb, wtb, rowmap, hdr, out);
    } else {
        hipMemsetAsync(hdr, 0, 16, stream);
        detect_mask_fmt<<<64, 256, 0, stream>>>((const unsigned*)mask, hdr);
        fallback_matvec<<<TOKENS, 256, 0, stream>>>(x, mask, w_v, w_t, hdr, out);
    }
}